// Round 14
// baseline (239.477 us; speedup 1.0000x reference)
//
#include <hip/hip_runtime.h>
#include <math.h>

#define NN 102400
#define NE 1638400
#define NG 2048
#define KTOP 30
#define NBUCK 400   // coarse buckets of 256 nodes (dst >> 8)
#define EPB 4096    // edges per pass-1 block
#define NB1 400     // NE / EPB

// ---------- fused front: coarse histogram + dense1 (LDS-staged x) + starts ----------
__global__ __launch_bounds__(256) void fused_front_kernel(
    const int* __restrict__ dst, int* __restrict__ hist1,
    const float* __restrict__ x, const float* __restrict__ W1,
    float* __restrict__ htmp,
    const int* __restrict__ batch, int* __restrict__ starts) {
    __shared__ float Wsh[128 * 32];   // 16384 B
    __shared__ float Xs[128 * 33];    // 16896 B (pad 33 breaks bank alias)
    __shared__ int hsh[NBUCK];        // 1600 B
    int bid = blockIdx.x;
    int tid = threadIdx.x;

    if (bid < NB1) {
        // ---- H1: coarse histogram ----
        for (int q = tid; q < NBUCK; q += 256) hsh[q] = 0;
        __syncthreads();
        const int4* dp = (const int4*)(dst + bid * EPB);
        for (int i4 = tid; i4 < EPB / 4; i4 += 256) {
            int4 dd = dp[i4];
            atomicAdd(&hsh[dd.x >> 8], 1);
            atomicAdd(&hsh[dd.y >> 8], 1);
            atomicAdd(&hsh[dd.z >> 8], 1);
            atomicAdd(&hsh[dd.w >> 8], 1);
        }
        __syncthreads();
        for (int q = tid; q < NBUCK; q += 256) hist1[q * NB1 + bid] = hsh[q];
    } else if (bid < NB1 + 800) {
        // ---- dense1: 128 -> 32; x staged via LDS (coalesced; r12/r13 lesson) ----
        int bidx = bid - NB1;
        int n_base = bidx * 128;
        for (int i = tid; i < 128 * 32; i += 256) Wsh[i] = W1[i];
        int jb = (tid >> 6) << 3;   // wave-uniform
        int q = tid & 63;
        float acc0[8], acc1[8];
#pragma unroll
        for (int j = 0; j < 8; ++j) { acc0[j] = 0.f; acc1[j] = 0.f; }
        for (int k0 = 0; k0 < 128; k0 += 32) {
            __syncthreads();
#pragma unroll
            for (int it = 0; it < 4; ++it) {
                int u = tid + 256 * it;       // 0..1023
                int row = u >> 3;             // 0..127
                int c4 = u & 7;               // 0..7
                float4 v = *(const float4*)&x[(size_t)(n_base + row) * 128 + k0 + c4 * 4];
                *(float4*)&Xs[row * 33 + c4 * 4] = v;
            }
            __syncthreads();
#pragma unroll 8
            for (int kk = 0; kk < 32; ++kk) {
                float v0 = Xs[q * 33 + kk];
                float v1 = Xs[(q + 64) * 33 + kk];
                float4 wlo = *(const float4*)&Wsh[(k0 + kk) * 32 + jb];
                float4 whi = *(const float4*)&Wsh[(k0 + kk) * 32 + jb + 4];
                acc0[0] += v0 * wlo.x; acc0[1] += v0 * wlo.y;
                acc0[2] += v0 * wlo.z; acc0[3] += v0 * wlo.w;
                acc0[4] += v0 * whi.x; acc0[5] += v0 * whi.y;
                acc0[6] += v0 * whi.z; acc0[7] += v0 * whi.w;
                acc1[0] += v1 * wlo.x; acc1[1] += v1 * wlo.y;
                acc1[2] += v1 * wlo.z; acc1[3] += v1 * wlo.w;
                acc1[4] += v1 * whi.x; acc1[5] += v1 * whi.y;
                acc1[6] += v1 * whi.z; acc1[7] += v1 * whi.w;
            }
        }
        int n0 = n_base + q;
        int n1 = n0 + 64;
        float4 o0 = {acc0[0], acc0[1], acc0[2], acc0[3]};
        float4 o1 = {acc0[4], acc0[5], acc0[6], acc0[7]};
        float4 o2 = {acc1[0], acc1[1], acc1[2], acc1[3]};
        float4 o3 = {acc1[4], acc1[5], acc1[6], acc1[7]};
        *(float4*)&htmp[(size_t)n0 * 32 + jb] = o0;
        *(float4*)&htmp[(size_t)n0 * 32 + jb + 4] = o1;
        *(float4*)&htmp[(size_t)n1 * 32 + jb] = o2;
        *(float4*)&htmp[(size_t)n1 * 32 + jb + 4] = o3;
    } else {
        // ---- starts ----
        int i = (bid - NB1 - 800) * 256 + tid;
        if (i < NN) {
            int c = batch[i];
            int p = (i == 0) ? -1 : batch[i - 1];
            for (int g = p + 1; g <= c; ++g) starts[g] = i;
            if (i == NN - 1) {
                for (int g = c + 1; g <= NG; ++g) starts[g] = NN;
            }
        }
    }
}

// ---------- S1a ----------
__global__ __launch_bounds__(256) void s1a_kernel(const int* __restrict__ hist1,
                                                  int* __restrict__ offs,
                                                  int* __restrict__ totals) {
    __shared__ int A[512], B[512];
    int q = blockIdx.x, tid = threadIdx.x;
    int i0 = tid, i1 = tid + 256;
    int v0 = (i0 < NB1) ? hist1[q * NB1 + i0] : 0;
    int v1 = (i1 < NB1) ? hist1[q * NB1 + i1] : 0;
    A[i0] = v0; A[i1] = v1;
    __syncthreads();
    int* cur = A; int* nxt = B;
    for (int off = 1; off < 512; off <<= 1) {
        nxt[i0] = cur[i0] + ((i0 >= off) ? cur[i0 - off] : 0);
        nxt[i1] = cur[i1] + cur[i1 - off];
        __syncthreads();
        int* t = cur; cur = nxt; nxt = t;
    }
    if (i0 < NB1) offs[q * NB1 + i0] = cur[i0] - v0;
    if (i1 < NB1) offs[q * NB1 + i1] = cur[i1] - v1;
    if (tid == 0) totals[q] = cur[511];
}

// ---------- S1b ----------
__global__ __launch_bounds__(256) void s1b_kernel(const int* __restrict__ totals,
                                                  int* __restrict__ bucketStart,
                                                  int* __restrict__ rowptr) {
    __shared__ int A[512], B[512];
    int tid = threadIdx.x;
    int i0 = tid, i1 = tid + 256;
    int v0 = (i0 < NBUCK) ? totals[i0] : 0;
    int v1 = (i1 < NBUCK) ? totals[i1] : 0;
    A[i0] = v0; A[i1] = v1;
    __syncthreads();
    int* cur = A; int* nxt = B;
    for (int off = 1; off < 512; off <<= 1) {
        nxt[i0] = cur[i0] + ((i0 >= off) ? cur[i0 - off] : 0);
        nxt[i1] = cur[i1] + cur[i1 - off];
        __syncthreads();
        int* t = cur; cur = nxt; nxt = t;
    }
    if (i0 < NBUCK) bucketStart[i0] = cur[i0] - v0;
    if (i1 < NBUCK) bucketStart[i1] = cur[i1] - v1;
    if (tid == 0) { bucketStart[NBUCK] = cur[511]; rowptr[NN] = cur[511]; }
}

// ---------- P1 ----------
__global__ __launch_bounds__(256) void p1_kernel(const int* __restrict__ src,
                                                 const int* __restrict__ dst,
                                                 const int* __restrict__ offs,
                                                 const int* __restrict__ bucketStart,
                                                 unsigned int* __restrict__ ebuf) {
    __shared__ int myoff[NBUCK];
    int b = blockIdx.x, tid = threadIdx.x;
    for (int q = tid; q < NBUCK; q += 256)
        myoff[q] = bucketStart[q] + offs[q * NB1 + b];
    __syncthreads();
    const int4* dp = (const int4*)(dst + b * EPB);
    const int4* sp = (const int4*)(src + b * EPB);
    for (int i4 = tid; i4 < EPB / 4; i4 += 256) {
        int4 dd = dp[i4];
        int4 ss = sp[i4];
        int p0 = atomicAdd(&myoff[dd.x >> 8], 1);
        int p1 = atomicAdd(&myoff[dd.y >> 8], 1);
        int p2 = atomicAdd(&myoff[dd.z >> 8], 1);
        int p3 = atomicAdd(&myoff[dd.w >> 8], 1);
        ebuf[p0] = ((unsigned int)(dd.x & 255) << 24) | (unsigned int)ss.x;
        ebuf[p1] = ((unsigned int)(dd.y & 255) << 24) | (unsigned int)ss.y;
        ebuf[p2] = ((unsigned int)(dd.z & 255) << 24) | (unsigned int)ss.z;
        ebuf[p3] = ((unsigned int)(dd.w & 255) << 24) | (unsigned int)ss.w;
    }
}

// ---------- P2a: per-bucket histogram -> rowptr + dinv (no scatter) ----------
__global__ __launch_bounds__(256) void p2a_kernel(const unsigned int* __restrict__ ebuf,
                                                  const int* __restrict__ bucketStart,
                                                  int* __restrict__ rowptr,
                                                  float* __restrict__ dinv) {
    __shared__ int fcnt[256];
    __shared__ int tmp[256];
    int q = blockIdx.x, tid = threadIdx.x;
    int base = bucketStart[q];
    int ecnt = bucketStart[q + 1] - base;
    fcnt[tid] = 0;
    __syncthreads();
    for (int i = tid; i < ecnt; i += 256) {
        unsigned int e = ebuf[base + i];
        atomicAdd(&fcnt[e >> 24], 1);
    }
    __syncthreads();
    int c = fcnt[tid];
    int n = q * 256 + tid;
    dinv[n] = rsqrtf((float)c + 1.0f);
    tmp[tid] = c;
    __syncthreads();
    for (int off = 1; off < 256; off <<= 1) {
        int u = (tid >= off) ? tmp[tid - off] : 0;
        __syncthreads();
        tmp[tid] += u;
        __syncthreads();
    }
    rowptr[n] = base + tmp[tid] - c;   // exclusive
}

// ---------- P2b: scatter csr_src + precomputed coef (dinv complete by now) ----------
// coef = dinv[src]*dinv[dst] here ONCE (1.6M random dinv gathers) instead of in
// all 4 agg layers (6.5M). FP multiply commutative -> bit-exact vs agg-side.
__global__ __launch_bounds__(256) void p2b_kernel(const unsigned int* __restrict__ ebuf,
                                                  const int* __restrict__ bucketStart,
                                                  const int* __restrict__ rowptr,
                                                  const float* __restrict__ dinv,
                                                  int* __restrict__ csr_src,
                                                  float* __restrict__ csr_coef) {
    __shared__ int foff[256];
    __shared__ float sdinv[256];
    int q = blockIdx.x, tid = threadIdx.x;
    int base = bucketStart[q];
    int ecnt = bucketStart[q + 1] - base;
    int n = q * 256 + tid;
    foff[tid] = rowptr[n];
    sdinv[tid] = dinv[n];
    __syncthreads();
    for (int i = tid; i < ecnt; i += 256) {
        unsigned int e = ebuf[base + i];
        int dloc = e >> 24;
        int s = (int)(e & 0xFFFFFF);
        int pos = atomicAdd(&foff[dloc], 1);
        csr_src[pos] = s;
        csr_coef[pos] = dinv[s] * sdinv[dloc];
    }
}

// ---------- fused gather-aggregate + tanh + NEXT-layer dense epilogue ----------
// coef read from csr_coef (broadcast loads) -> no per-edge dinv gathers.
template <int NEXT>  // 32 (-> full 32x32 dense) or 1 (-> 32->1 dense)
__global__ __launch_bounds__(256) void gcn_aggd_kernel(
    const int* __restrict__ rowptr, const int* __restrict__ csr_src,
    const float* __restrict__ csr_coef, const float* __restrict__ htmp,
    const float* __restrict__ dinv, const float* __restrict__ b,
    const float* __restrict__ Wn, float* __restrict__ hout,
    float* __restrict__ htn) {
    __shared__ float Ws[32 * 32];
    __shared__ float Hs[32][36];
    int tid = threadIdx.x;
    if (NEXT == 32) {
        for (int i = tid; i < 1024; i += 256) Ws[i] = Wn[i];
    } else {
        if (tid < 32) Ws[tid] = Wn[tid];
    }
    int idx = blockIdx.x * 256 + tid;
    int n = idx >> 3, fg = (idx & 7) << 2;
    int beg = rowptr[n], end = rowptr[n + 1];
    float di = dinv[n];
    float4 acc = {0.f, 0.f, 0.f, 0.f};
    int i = beg;
    for (; i + 7 < end; i += 8) {
        int s[8];
#pragma unroll
        for (int k = 0; k < 8; ++k) s[k] = csr_src[i + k];
        float c[8];
#pragma unroll
        for (int k = 0; k < 8; ++k) c[k] = csr_coef[i + k];
        float4 v[8];
#pragma unroll
        for (int k = 0; k < 8; ++k) v[k] = *(const float4*)&htmp[(size_t)s[k] * 32 + fg];
#pragma unroll
        for (int k = 0; k < 8; ++k) {
            acc.x += v[k].x * c[k]; acc.y += v[k].y * c[k];
            acc.z += v[k].z * c[k]; acc.w += v[k].w * c[k];
        }
    }
    for (; i + 3 < end; i += 4) {
        int s0 = csr_src[i], s1 = csr_src[i + 1];
        int s2 = csr_src[i + 2], s3 = csr_src[i + 3];
        float c0 = csr_coef[i], c1 = csr_coef[i + 1];
        float c2 = csr_coef[i + 2], c3 = csr_coef[i + 3];
        float4 v0 = *(const float4*)&htmp[(size_t)s0 * 32 + fg];
        float4 v1 = *(const float4*)&htmp[(size_t)s1 * 32 + fg];
        float4 v2 = *(const float4*)&htmp[(size_t)s2 * 32 + fg];
        float4 v3 = *(const float4*)&htmp[(size_t)s3 * 32 + fg];
        acc.x += v0.x * c0; acc.y += v0.y * c0; acc.z += v0.z * c0; acc.w += v0.w * c0;
        acc.x += v1.x * c1; acc.y += v1.y * c1; acc.z += v1.z * c1; acc.w += v1.w * c1;
        acc.x += v2.x * c2; acc.y += v2.y * c2; acc.z += v2.z * c2; acc.w += v2.w * c2;
        acc.x += v3.x * c3; acc.y += v3.y * c3; acc.z += v3.z * c3; acc.w += v3.w * c3;
    }
    for (; i < end; ++i) {
        int s = csr_src[i];
        float c = csr_coef[i];
        float4 v = *(const float4*)&htmp[(size_t)s * 32 + fg];
        acc.x += v.x * c; acc.y += v.y * c; acc.z += v.z * c; acc.w += v.w * c;
    }
    float dd = di * di;
    float4 hs = *(const float4*)&htmp[(size_t)n * 32 + fg];
    float4 bb = *(const float4*)&b[fg];
    float4 o;
    o.x = tanhf(acc.x + hs.x * dd + bb.x);
    o.y = tanhf(acc.y + hs.y * dd + bb.y);
    o.z = tanhf(acc.z + hs.z * dd + bb.z);
    o.w = tanhf(acc.w + hs.w * dd + bb.w);
    *(float4*)&hout[(size_t)n * 32 + fg] = o;
    int nl = tid >> 3;
    *(float4*)&Hs[nl][fg] = o;
    __syncthreads();
    if (NEXT == 32) {
        int n2 = tid >> 3, j4 = (tid & 7) << 2;
        int gnode = blockIdx.x * 32 + n2;
        float4 r = {0.f, 0.f, 0.f, 0.f};
#pragma unroll
        for (int k = 0; k < 32; ++k) {
            float h = Hs[n2][k];
            float4 wv = *(const float4*)&Ws[k * 32 + j4];
            r.x += h * wv.x; r.y += h * wv.y; r.z += h * wv.z; r.w += h * wv.w;
        }
        *(float4*)&htn[(size_t)gnode * 32 + j4] = r;
    } else {
        if (tid < 32) {
            int gnode = blockIdx.x * 32 + tid;
            float s = 0.f;
#pragma unroll
            for (int k = 0; k < 32; ++k) s += Hs[tid][k] * Ws[k];
            htn[gnode] = s;
        }
    }
}

__global__ __launch_bounds__(256) void gcn_agg1_kernel(
    const int* __restrict__ rowptr, const int* __restrict__ csr_src,
    const float* __restrict__ csr_coef, const float* __restrict__ htmp,
    const float* __restrict__ dinv, const float* __restrict__ b,
    float* __restrict__ hout) {
    int n = blockIdx.x * blockDim.x + threadIdx.x;
    if (n >= NN) return;
    int beg = rowptr[n], end = rowptr[n + 1];
    float di = dinv[n];
    float acc = 0.f;
    int i = beg;
    for (; i + 7 < end; i += 8) {
        int s[8];
#pragma unroll
        for (int k = 0; k < 8; ++k) s[k] = csr_src[i + k];
        float c[8], v[8];
#pragma unroll
        for (int k = 0; k < 8; ++k) c[k] = csr_coef[i + k];
#pragma unroll
        for (int k = 0; k < 8; ++k) v[k] = htmp[s[k]];
#pragma unroll
        for (int k = 0; k < 8; ++k) acc += v[k] * c[k];
    }
    for (; i < end; ++i) {
        acc += htmp[csr_src[i]] * csr_coef[i];
    }
    hout[n] = tanhf(acc + htmp[n] * di * di + b[0]);
}

// ---------- sort-pool + CNN head: r9's proven monolith ----------

#define PSTR 100

__global__ __launch_bounds__(256) void pool_cnn_kernel(
    const float* __restrict__ h1, const float* __restrict__ h2,
    const float* __restrict__ h3, const float* __restrict__ h4,
    const int* __restrict__ starts,
    const float* __restrict__ c1w, const float* __restrict__ c1b,
    const float* __restrict__ c2w, const float* __restrict__ c2b,
    const float* __restrict__ l1w, const float* __restrict__ l1b,
    const float* __restrict__ l2w, const float* __restrict__ l2b,
    float* __restrict__ out) {
    __shared__ float P[KTOP][PSTR];
    __shared__ float CW[16 * PSTR];
    __shared__ float KY[480];
    __shared__ int   sel_node[KTOP];
    __shared__ float sel_key[KTOP];
    float* keys = KY;
    float* y2 = &P[0][0];
    float* y3 = &P[0][0] + 240;
    float* z  = &P[0][0] + 592;
    int g = blockIdx.x;
    int tid = threadIdx.x;

    int start = starts[g];
    int end = starts[g + 1];
    int cnt = end - start;

    for (int i = tid; i < KTOP * PSTR; i += 256) (&P[0][0])[i] = 0.f;
    for (int i = tid; i < 16 * 97; i += 256) {
        int c = i / 97, f = i % 97;
        CW[c * PSTR + f] = c1w[i];
    }
    bool fits = (cnt <= 480);
    if (fits) {
        for (int i = tid; i < cnt; i += 256) keys[i] = h4[start + i];
    }
    __syncthreads();

    for (int i = tid; i < cnt; i += 256) {
        float key = fits ? keys[i] : h4[start + i];
        int rank = 0;
        if (fits) {
            for (int j = 0; j < cnt; ++j) {
                float kj = keys[j];
                rank += (kj > key) || (kj == key && j < i);
            }
        } else {
            for (int j = 0; j < cnt; ++j) {
                float kj = h4[start + j];
                rank += (kj > key) || (kj == key && j < i);
            }
        }
        if (rank < KTOP) {
            sel_node[rank] = start + i;
            sel_key[rank] = key;
        }
    }
    __syncthreads();

    int nsel = (cnt < KTOP) ? cnt : KTOP;
    for (int u = tid; u < nsel * 24; u += 256) {
        int r = u / 24, q = u % 24;
        int node = sel_node[r];
        const float* srcp = (q < 8) ? h1 : (q < 16) ? h2 : h3;
        int qq = q & 7;
        float4 v = *(const float4*)(srcp + (size_t)node * 32 + 4 * qq);
        *(float4*)&P[r][(q < 8 ? 0 : (q < 16 ? 32 : 64)) + 4 * qq] = v;
    }
    for (int r = tid; r < nsel; r += 256) P[r][96] = sel_key[r];
    __syncthreads();

    for (int o = tid; o < 16 * KTOP; o += 256) {
        int t = o >> 4, c = o & 15;
        float s = c1b[c];
        const float* Pr = &P[t][0];
        const float* Wr = &CW[c * PSTR];
#pragma unroll
        for (int f4 = 0; f4 < 24; ++f4) {
            float4 pv = *(const float4*)(Pr + 4 * f4);
            float4 wv = *(const float4*)(Wr + 4 * f4);
            s += wv.x * pv.x; s += wv.y * pv.y; s += wv.z * pv.z; s += wv.w * pv.w;
        }
        s += Wr[96] * Pr[96];
        KY[c * KTOP + t] = fmaxf(s, 0.f);
    }
    __syncthreads();

    for (int o = tid; o < 16 * 15; o += 256) {
        int c = o / 15, t = o % 15;
        y2[o] = fmaxf(KY[c * KTOP + 2 * t], KY[c * KTOP + 2 * t + 1]);
    }
    __syncthreads();

    for (int o = tid; o < 32 * 11; o += 256) {
        int c = o / 11, t = o % 11;
        float s = c2b[c];
#pragma unroll
        for (int i = 0; i < 16; ++i)
#pragma unroll
            for (int j = 0; j < 5; ++j)
                s += c2w[(c * 16 + i) * 5 + j] * y2[i * 15 + t + j];
        y3[o] = fmaxf(s, 0.f);
    }
    __syncthreads();

    for (int o = tid; o < 128; o += 256) {
        float s = l1b[o];
#pragma unroll 16
        for (int i = 0; i < 352; ++i) s += y3[i] * l1w[i * 128 + o];
        z[o] = fmaxf(s, 0.f);
    }
    __syncthreads();

    if (tid == 0) {
        float s = l2b[0];
#pragma unroll 4
        for (int i = 0; i < 128; ++i) s += z[i] * l2w[i];
        out[g] = 1.f / (1.f + expf(-s));
    }
}

extern "C" void kernel_launch(void* const* d_in, const int* in_sizes, int n_in,
                              void* d_out, int out_size, void* d_ws, size_t ws_size,
                              hipStream_t stream) {
    const float* x   = (const float*)d_in[0];
    const int* ei    = (const int*)d_in[1];
    const int* batch = (const int*)d_in[2];
    const float* W1  = (const float*)d_in[3];
    const float* b1  = (const float*)d_in[4];
    const float* W2  = (const float*)d_in[5];
    const float* b2  = (const float*)d_in[6];
    const float* W3  = (const float*)d_in[7];
    const float* b3  = (const float*)d_in[8];
    const float* W4  = (const float*)d_in[9];
    const float* b4  = (const float*)d_in[10];
    const float* c1w = (const float*)d_in[11];
    const float* c1b = (const float*)d_in[12];
    const float* c2w = (const float*)d_in[13];
    const float* c2b = (const float*)d_in[14];
    const float* l1w = (const float*)d_in[15];
    const float* l1b = (const float*)d_in[16];
    const float* l2w = (const float*)d_in[17];
    const float* l2b = (const float*)d_in[18];
    float* out = (float*)d_out;

    const int* srcp = ei;
    const int* dstp = ei + NE;

    // workspace layout
    char* w = (char*)d_ws;
    float* dinv      = (float*)w;               w += sizeof(float) * NN;
    float* htmpA     = (float*)w;               w += sizeof(float) * NN * 32;
    float* htmpB     = (float*)w;               w += sizeof(float) * NN * 32;
    float* h1        = (float*)w;               w += sizeof(float) * NN * 32;
    float* h2        = (float*)w;               w += sizeof(float) * NN * 32;  // ebuf aliases here
    float* h3        = (float*)w;               w += sizeof(float) * NN * 32;
    float* h4        = (float*)w;               w += sizeof(float) * NN;
    int*   rowptr    = (int*)w;                 w += sizeof(int) * (NN + 1);
    int*   hist1     = (int*)w;                 w += sizeof(int) * NBUCK * NB1;
    int*   offs      = (int*)w;                 w += sizeof(int) * NBUCK * NB1;
    int*   totals    = (int*)w;                 w += sizeof(int) * NBUCK;
    int*   bucketStart = (int*)w;               w += sizeof(int) * (NBUCK + 1);
    int*   csr_src   = (int*)w;                 w += sizeof(int) * NE;
    float* csr_coef  = (float*)w;               w += sizeof(float) * NE;
    int*   starts    = (int*)w;                 w += sizeof(int) * (NG + 1);

    // ebuf (6.55 MB) aliases h2 (13.1 MB): h2 first written at layer-2 agg,
    // long after p2b consumes ebuf.
    unsigned int* ebuf = (unsigned int*)h2;

    // CSR build (no global atomics) + dense1 + starts
    fused_front_kernel<<<NB1 + 800 + 400, 256, 0, stream>>>(dstp, hist1, x, W1, htmpA,
                                                            batch, starts);
    s1a_kernel<<<NBUCK, 256, 0, stream>>>(hist1, offs, totals);
    s1b_kernel<<<1, 256, 0, stream>>>(totals, bucketStart, rowptr);
    p1_kernel<<<NB1, 256, 0, stream>>>(srcp, dstp, offs, bucketStart, ebuf);
    p2a_kernel<<<NBUCK, 256, 0, stream>>>(ebuf, bucketStart, rowptr, dinv);
    p2b_kernel<<<NBUCK, 256, 0, stream>>>(ebuf, bucketStart, rowptr, dinv,
                                          csr_src, csr_coef);

    // layer 1 agg (+ fused dense W2): htmpA -> h1, htmpB
    gcn_aggd_kernel<32><<<NN / 32, 256, 0, stream>>>(rowptr, csr_src, csr_coef, htmpA,
                                                     dinv, b1, W2, h1, htmpB);
    // layer 2 agg (+ fused dense W3): htmpB -> h2, htmpA
    gcn_aggd_kernel<32><<<NN / 32, 256, 0, stream>>>(rowptr, csr_src, csr_coef, htmpB,
                                                     dinv, b2, W3, h2, htmpA);
    // layer 3 agg (+ fused dense W4 32->1): htmpA -> h3, htmpB[0:NN]
    gcn_aggd_kernel<1><<<NN / 32, 256, 0, stream>>>(rowptr, csr_src, csr_coef, htmpA,
                                                    dinv, b3, W4, h3, htmpB);
    // layer 4 agg: htmpB[0:NN] -> h4
    gcn_agg1_kernel<<<NN / 256, 256, 0, stream>>>(rowptr, csr_src, csr_coef, htmpB,
                                                  dinv, b4, h4);

    // fused sort-pool + CNN head
    pool_cnn_kernel<<<NG, 256, 0, stream>>>(h1, h2, h3, h4, starts,
                                            c1w, c1b, c2w, c2b,
                                            l1w, l1b, l2w, l2b, out);
}

// Round 15
// 225.554 us; speedup vs baseline: 1.0617x; 1.0617x over previous
//
#include <hip/hip_runtime.h>
#include <math.h>

#define NN 102400
#define NE 1638400
#define NG 2048
#define KTOP 30
#define NBUCK 400   // coarse buckets of 256 nodes (dst >> 8)
#define EPB 4096    // edges per pass-1 block
#define NB1 400     // NE / EPB

// ---------- fused front: coarse histogram + dense1 (LDS-staged x) + starts ----------
__global__ __launch_bounds__(256) void fused_front_kernel(
    const int* __restrict__ dst, int* __restrict__ hist1,
    const float* __restrict__ x, const float* __restrict__ W1,
    float* __restrict__ htmp,
    const int* __restrict__ batch, int* __restrict__ starts) {
    __shared__ float Wsh[128 * 32];   // 16384 B
    __shared__ float Xs[128 * 33];    // 16896 B (pad 33 breaks bank alias)
    __shared__ int hsh[NBUCK];        // 1600 B
    int bid = blockIdx.x;
    int tid = threadIdx.x;

    if (bid < NB1) {
        // ---- H1: coarse histogram ----
        for (int q = tid; q < NBUCK; q += 256) hsh[q] = 0;
        __syncthreads();
        const int4* dp = (const int4*)(dst + bid * EPB);
        for (int i4 = tid; i4 < EPB / 4; i4 += 256) {
            int4 dd = dp[i4];
            atomicAdd(&hsh[dd.x >> 8], 1);
            atomicAdd(&hsh[dd.y >> 8], 1);
            atomicAdd(&hsh[dd.z >> 8], 1);
            atomicAdd(&hsh[dd.w >> 8], 1);
        }
        __syncthreads();
        for (int q = tid; q < NBUCK; q += 256) hist1[q * NB1 + bid] = hsh[q];
    } else if (bid < NB1 + 800) {
        // ---- dense1: 128 -> 32; x staged via LDS (coalesced; r12/r13 lesson) ----
        int bidx = bid - NB1;
        int n_base = bidx * 128;
        for (int i = tid; i < 128 * 32; i += 256) Wsh[i] = W1[i];
        int jb = (tid >> 6) << 3;   // wave-uniform
        int q = tid & 63;
        float acc0[8], acc1[8];
#pragma unroll
        for (int j = 0; j < 8; ++j) { acc0[j] = 0.f; acc1[j] = 0.f; }
        for (int k0 = 0; k0 < 128; k0 += 32) {
            __syncthreads();
#pragma unroll
            for (int it = 0; it < 4; ++it) {
                int u = tid + 256 * it;       // 0..1023
                int row = u >> 3;             // 0..127
                int c4 = u & 7;               // 0..7
                float4 v = *(const float4*)&x[(size_t)(n_base + row) * 128 + k0 + c4 * 4];
                *(float4*)&Xs[row * 33 + c4 * 4] = v;
            }
            __syncthreads();
#pragma unroll 8
            for (int kk = 0; kk < 32; ++kk) {
                float v0 = Xs[q * 33 + kk];
                float v1 = Xs[(q + 64) * 33 + kk];
                float4 wlo = *(const float4*)&Wsh[(k0 + kk) * 32 + jb];
                float4 whi = *(const float4*)&Wsh[(k0 + kk) * 32 + jb + 4];
                acc0[0] += v0 * wlo.x; acc0[1] += v0 * wlo.y;
                acc0[2] += v0 * wlo.z; acc0[3] += v0 * wlo.w;
                acc0[4] += v0 * whi.x; acc0[5] += v0 * whi.y;
                acc0[6] += v0 * whi.z; acc0[7] += v0 * whi.w;
                acc1[0] += v1 * wlo.x; acc1[1] += v1 * wlo.y;
                acc1[2] += v1 * wlo.z; acc1[3] += v1 * wlo.w;
                acc1[4] += v1 * whi.x; acc1[5] += v1 * whi.y;
                acc1[6] += v1 * whi.z; acc1[7] += v1 * whi.w;
            }
        }
        int n0 = n_base + q;
        int n1 = n0 + 64;
        float4 o0 = {acc0[0], acc0[1], acc0[2], acc0[3]};
        float4 o1 = {acc0[4], acc0[5], acc0[6], acc0[7]};
        float4 o2 = {acc1[0], acc1[1], acc1[2], acc1[3]};
        float4 o3 = {acc1[4], acc1[5], acc1[6], acc1[7]};
        *(float4*)&htmp[(size_t)n0 * 32 + jb] = o0;
        *(float4*)&htmp[(size_t)n0 * 32 + jb + 4] = o1;
        *(float4*)&htmp[(size_t)n1 * 32 + jb] = o2;
        *(float4*)&htmp[(size_t)n1 * 32 + jb + 4] = o3;
    } else {
        // ---- starts ----
        int i = (bid - NB1 - 800) * 256 + tid;
        if (i < NN) {
            int c = batch[i];
            int p = (i == 0) ? -1 : batch[i - 1];
            for (int g = p + 1; g <= c; ++g) starts[g] = i;
            if (i == NN - 1) {
                for (int g = c + 1; g <= NG; ++g) starts[g] = NN;
            }
        }
    }
}

// ---------- S1a ----------
__global__ __launch_bounds__(256) void s1a_kernel(const int* __restrict__ hist1,
                                                  int* __restrict__ offs,
                                                  int* __restrict__ totals) {
    __shared__ int A[512], B[512];
    int q = blockIdx.x, tid = threadIdx.x;
    int i0 = tid, i1 = tid + 256;
    int v0 = (i0 < NB1) ? hist1[q * NB1 + i0] : 0;
    int v1 = (i1 < NB1) ? hist1[q * NB1 + i1] : 0;
    A[i0] = v0; A[i1] = v1;
    __syncthreads();
    int* cur = A; int* nxt = B;
    for (int off = 1; off < 512; off <<= 1) {
        nxt[i0] = cur[i0] + ((i0 >= off) ? cur[i0 - off] : 0);
        nxt[i1] = cur[i1] + cur[i1 - off];
        __syncthreads();
        int* t = cur; cur = nxt; nxt = t;
    }
    if (i0 < NB1) offs[q * NB1 + i0] = cur[i0] - v0;
    if (i1 < NB1) offs[q * NB1 + i1] = cur[i1] - v1;
    if (tid == 0) totals[q] = cur[511];
}

// ---------- S1b ----------
__global__ __launch_bounds__(256) void s1b_kernel(const int* __restrict__ totals,
                                                  int* __restrict__ bucketStart,
                                                  int* __restrict__ rowptr) {
    __shared__ int A[512], B[512];
    int tid = threadIdx.x;
    int i0 = tid, i1 = tid + 256;
    int v0 = (i0 < NBUCK) ? totals[i0] : 0;
    int v1 = (i1 < NBUCK) ? totals[i1] : 0;
    A[i0] = v0; A[i1] = v1;
    __syncthreads();
    int* cur = A; int* nxt = B;
    for (int off = 1; off < 512; off <<= 1) {
        nxt[i0] = cur[i0] + ((i0 >= off) ? cur[i0 - off] : 0);
        nxt[i1] = cur[i1] + cur[i1 - off];
        __syncthreads();
        int* t = cur; cur = nxt; nxt = t;
    }
    if (i0 < NBUCK) bucketStart[i0] = cur[i0] - v0;
    if (i1 < NBUCK) bucketStart[i1] = cur[i1] - v1;
    if (tid == 0) { bucketStart[NBUCK] = cur[511]; rowptr[NN] = cur[511]; }
}

// ---------- P1 ----------
__global__ __launch_bounds__(256) void p1_kernel(const int* __restrict__ src,
                                                 const int* __restrict__ dst,
                                                 const int* __restrict__ offs,
                                                 const int* __restrict__ bucketStart,
                                                 unsigned int* __restrict__ ebuf) {
    __shared__ int myoff[NBUCK];
    int b = blockIdx.x, tid = threadIdx.x;
    for (int q = tid; q < NBUCK; q += 256)
        myoff[q] = bucketStart[q] + offs[q * NB1 + b];
    __syncthreads();
    const int4* dp = (const int4*)(dst + b * EPB);
    const int4* sp = (const int4*)(src + b * EPB);
    for (int i4 = tid; i4 < EPB / 4; i4 += 256) {
        int4 dd = dp[i4];
        int4 ss = sp[i4];
        int p0 = atomicAdd(&myoff[dd.x >> 8], 1);
        int p1 = atomicAdd(&myoff[dd.y >> 8], 1);
        int p2 = atomicAdd(&myoff[dd.z >> 8], 1);
        int p3 = atomicAdd(&myoff[dd.w >> 8], 1);
        ebuf[p0] = ((unsigned int)(dd.x & 255) << 24) | (unsigned int)ss.x;
        ebuf[p1] = ((unsigned int)(dd.y & 255) << 24) | (unsigned int)ss.y;
        ebuf[p2] = ((unsigned int)(dd.z & 255) << 24) | (unsigned int)ss.z;
        ebuf[p3] = ((unsigned int)(dd.w & 255) << 24) | (unsigned int)ss.w;
    }
}

// ---------- P2 ----------
__global__ __launch_bounds__(256) void p2_kernel(const unsigned int* __restrict__ ebuf,
                                                 const int* __restrict__ bucketStart,
                                                 int* __restrict__ csr_src,
                                                 int* __restrict__ rowptr,
                                                 float* __restrict__ dinv) {
    __shared__ int fcnt[256];
    __shared__ int tmp[256];
    __shared__ int foff[256];
    int q = blockIdx.x, tid = threadIdx.x;
    int base = bucketStart[q];
    int ecnt = bucketStart[q + 1] - base;
    fcnt[tid] = 0;
    __syncthreads();
    for (int i = tid; i < ecnt; i += 256) {
        unsigned int e = ebuf[base + i];
        atomicAdd(&fcnt[e >> 24], 1);
    }
    __syncthreads();
    int c = fcnt[tid];
    int n = q * 256 + tid;
    dinv[n] = rsqrtf((float)c + 1.0f);
    tmp[tid] = c;
    __syncthreads();
    for (int off = 1; off < 256; off <<= 1) {
        int u = (tid >= off) ? tmp[tid - off] : 0;
        __syncthreads();
        tmp[tid] += u;
        __syncthreads();
    }
    int excl = base + tmp[tid] - c;
    rowptr[n] = excl;
    foff[tid] = excl;
    __syncthreads();
    for (int i = tid; i < ecnt; i += 256) {
        unsigned int e = ebuf[base + i];
        int pos = atomicAdd(&foff[e >> 24], 1);
        csr_src[pos] = (int)(e & 0xFFFFFF);
    }
}

// ---------- fused gather-aggregate + tanh + NEXT-layer dense epilogue ----------
template <int NEXT>  // 32 (-> full 32x32 dense) or 1 (-> 32->1 dense)
__global__ __launch_bounds__(256) void gcn_aggd_kernel(
    const int* __restrict__ rowptr, const int* __restrict__ csr_src,
    const float* __restrict__ htmp, const float* __restrict__ dinv,
    const float* __restrict__ b, const float* __restrict__ Wn,
    float* __restrict__ hout, float* __restrict__ htn) {
    __shared__ float Ws[32 * 32];
    __shared__ float Hs[32][36];
    int tid = threadIdx.x;
    if (NEXT == 32) {
        for (int i = tid; i < 1024; i += 256) Ws[i] = Wn[i];
    } else {
        if (tid < 32) Ws[tid] = Wn[tid];
    }
    int idx = blockIdx.x * 256 + tid;
    int n = idx >> 3, fg = (idx & 7) << 2;
    int beg = rowptr[n], end = rowptr[n + 1];
    float di = dinv[n];
    float4 acc = {0.f, 0.f, 0.f, 0.f};
    int i = beg;
    for (; i + 7 < end; i += 8) {
        int s[8];
#pragma unroll
        for (int k = 0; k < 8; ++k) s[k] = csr_src[i + k];
        float c[8];
#pragma unroll
        for (int k = 0; k < 8; ++k) c[k] = dinv[s[k]] * di;
        float4 v[8];
#pragma unroll
        for (int k = 0; k < 8; ++k) v[k] = *(const float4*)&htmp[(size_t)s[k] * 32 + fg];
#pragma unroll
        for (int k = 0; k < 8; ++k) {
            acc.x += v[k].x * c[k]; acc.y += v[k].y * c[k];
            acc.z += v[k].z * c[k]; acc.w += v[k].w * c[k];
        }
    }
    for (; i + 3 < end; i += 4) {
        int s0 = csr_src[i], s1 = csr_src[i + 1];
        int s2 = csr_src[i + 2], s3 = csr_src[i + 3];
        float c0 = dinv[s0] * di, c1 = dinv[s1] * di;
        float c2 = dinv[s2] * di, c3 = dinv[s3] * di;
        float4 v0 = *(const float4*)&htmp[(size_t)s0 * 32 + fg];
        float4 v1 = *(const float4*)&htmp[(size_t)s1 * 32 + fg];
        float4 v2 = *(const float4*)&htmp[(size_t)s2 * 32 + fg];
        float4 v3 = *(const float4*)&htmp[(size_t)s3 * 32 + fg];
        acc.x += v0.x * c0; acc.y += v0.y * c0; acc.z += v0.z * c0; acc.w += v0.w * c0;
        acc.x += v1.x * c1; acc.y += v1.y * c1; acc.z += v1.z * c1; acc.w += v1.w * c1;
        acc.x += v2.x * c2; acc.y += v2.y * c2; acc.z += v2.z * c2; acc.w += v2.w * c2;
        acc.x += v3.x * c3; acc.y += v3.y * c3; acc.z += v3.z * c3; acc.w += v3.w * c3;
    }
    for (; i < end; ++i) {
        int s = csr_src[i];
        float c = dinv[s] * di;
        float4 v = *(const float4*)&htmp[(size_t)s * 32 + fg];
        acc.x += v.x * c; acc.y += v.y * c; acc.z += v.z * c; acc.w += v.w * c;
    }
    float dd = di * di;
    float4 hs = *(const float4*)&htmp[(size_t)n * 32 + fg];
    float4 bb = *(const float4*)&b[fg];
    float4 o;
    o.x = tanhf(acc.x + hs.x * dd + bb.x);
    o.y = tanhf(acc.y + hs.y * dd + bb.y);
    o.z = tanhf(acc.z + hs.z * dd + bb.z);
    o.w = tanhf(acc.w + hs.w * dd + bb.w);
    *(float4*)&hout[(size_t)n * 32 + fg] = o;
    int nl = tid >> 3;
    *(float4*)&Hs[nl][fg] = o;
    __syncthreads();
    if (NEXT == 32) {
        int n2 = tid >> 3, j4 = (tid & 7) << 2;
        int gnode = blockIdx.x * 32 + n2;
        float4 r = {0.f, 0.f, 0.f, 0.f};
#pragma unroll
        for (int k = 0; k < 32; ++k) {
            float h = Hs[n2][k];
            float4 wv = *(const float4*)&Ws[k * 32 + j4];
            r.x += h * wv.x; r.y += h * wv.y; r.z += h * wv.z; r.w += h * wv.w;
        }
        *(float4*)&htn[(size_t)gnode * 32 + j4] = r;
    } else {
        if (tid < 32) {
            int gnode = blockIdx.x * 32 + tid;
            float s = 0.f;
#pragma unroll
            for (int k = 0; k < 32; ++k) s += Hs[tid][k] * Ws[k];
            htn[gnode] = s;
        }
    }
}

__global__ __launch_bounds__(256) void gcn_agg1_kernel(
    const int* __restrict__ rowptr, const int* __restrict__ csr_src,
    const float* __restrict__ htmp, const float* __restrict__ dinv,
    const float* __restrict__ b, float* __restrict__ hout) {
    int n = blockIdx.x * blockDim.x + threadIdx.x;
    if (n >= NN) return;
    int beg = rowptr[n], end = rowptr[n + 1];
    float di = dinv[n];
    float acc = 0.f;
    int i = beg;
    for (; i + 7 < end; i += 8) {
        int s[8];
#pragma unroll
        for (int k = 0; k < 8; ++k) s[k] = csr_src[i + k];
        float c[8], v[8];
#pragma unroll
        for (int k = 0; k < 8; ++k) c[k] = dinv[s[k]] * di;
#pragma unroll
        for (int k = 0; k < 8; ++k) v[k] = htmp[s[k]];
#pragma unroll
        for (int k = 0; k < 8; ++k) acc += v[k] * c[k];
    }
    for (; i < end; ++i) {
        int s = csr_src[i];
        acc += htmp[s] * (dinv[s] * di);
    }
    hout[n] = tanhf(acc + htmp[n] * di * di + b[0]);
}

// ---------- sort-pool + CNN head ----------
// LDS diet via P pad columns: sel_key -> P[r][96], sel_node -> P[r][97]
// (columns 96-99 unused by coop-fill/conv1's f<96 reads).
// LDS = P 12000 + CW 6400 + KY 1920 = 20320 -> block 20480 exactly
// -> 8 blocks/CU, whole 2048-block grid resident in ONE round.
// No launch_bounds pin (r10 lesson); float4 CW reads kept (r11 lesson).

#define PSTR 100

__global__ __launch_bounds__(256) void pool_cnn_kernel(
    const float* __restrict__ h1, const float* __restrict__ h2,
    const float* __restrict__ h3, const float* __restrict__ h4,
    const int* __restrict__ starts,
    const float* __restrict__ c1w, const float* __restrict__ c1b,
    const float* __restrict__ c2w, const float* __restrict__ c2b,
    const float* __restrict__ l1w, const float* __restrict__ l1b,
    const float* __restrict__ l2w, const float* __restrict__ l2b,
    float* __restrict__ out) {
    __shared__ float P[KTOP][PSTR];   // rows: [0..95]=feat, [96]=key, [97]=node
    __shared__ float CW[16 * PSTR];
    __shared__ float KY[480];
    float* keys = KY;
    float* y2 = &P[0][0];
    float* y3 = &P[0][0] + 240;
    float* z  = &P[0][0] + 592;
    int g = blockIdx.x;
    int tid = threadIdx.x;

    int start = starts[g];
    int end = starts[g + 1];
    int cnt = end - start;

    for (int i = tid; i < KTOP * PSTR; i += 256) (&P[0][0])[i] = 0.f;
    for (int i = tid; i < 16 * 97; i += 256) {
        int c = i / 97, f = i % 97;
        CW[c * PSTR + f] = c1w[i];
    }
    bool fits = (cnt <= 480);
    if (fits) {
        for (int i = tid; i < cnt; i += 256) keys[i] = h4[start + i];
    }
    __syncthreads();

    // rank; stash (key,node) in P's pad columns (ranks distinct -> no conflicts)
    for (int i = tid; i < cnt; i += 256) {
        float key = fits ? keys[i] : h4[start + i];
        int rank = 0;
        if (fits) {
            for (int j = 0; j < cnt; ++j) {
                float kj = keys[j];
                rank += (kj > key) || (kj == key && j < i);
            }
        } else {
            for (int j = 0; j < cnt; ++j) {
                float kj = h4[start + j];
                rank += (kj > key) || (kj == key && j < i);
            }
        }
        if (rank < KTOP) {
            P[rank][96] = key;
            P[rank][97] = __int_as_float(start + i);
        }
    }
    __syncthreads();

    // cooperative P-fill: nsel rows x 24 float4 over all 256 threads
    int nsel = (cnt < KTOP) ? cnt : KTOP;
    for (int u = tid; u < nsel * 24; u += 256) {
        int r = u / 24, q = u % 24;
        int node = __float_as_int(P[r][97]);
        const float* srcp = (q < 8) ? h1 : (q < 16) ? h2 : h3;
        int qq = q & 7;
        float4 v = *(const float4*)(srcp + (size_t)node * 32 + 4 * qq);
        *(float4*)&P[r][(q < 8 ? 0 : (q < 16 ? 32 : 64)) + 4 * qq] = v;
    }
    __syncthreads();

    // conv1: t=o>>4 mapping (4 distinct P rows per wave); f ascending -> bit-exact.
    for (int o = tid; o < 16 * KTOP; o += 256) {
        int t = o >> 4, c = o & 15;
        float s = c1b[c];
        const float* Pr = &P[t][0];
        const float* Wr = &CW[c * PSTR];
#pragma unroll
        for (int f4 = 0; f4 < 24; ++f4) {
            float4 pv = *(const float4*)(Pr + 4 * f4);
            float4 wv = *(const float4*)(Wr + 4 * f4);
            s += wv.x * pv.x; s += wv.y * pv.y; s += wv.z * pv.z; s += wv.w * pv.w;
        }
        s += Wr[96] * Pr[96];
        KY[c * KTOP + t] = fmaxf(s, 0.f);   // y1 (keys dead)
    }
    __syncthreads();

    for (int o = tid; o < 16 * 15; o += 256) {
        int c = o / 15, t = o % 15;
        y2[o] = fmaxf(KY[c * KTOP + 2 * t], KY[c * KTOP + 2 * t + 1]);
    }
    __syncthreads();

    for (int o = tid; o < 32 * 11; o += 256) {
        int c = o / 11, t = o % 11;
        float s = c2b[c];
#pragma unroll
        for (int i = 0; i < 16; ++i)
#pragma unroll
            for (int j = 0; j < 5; ++j)
                s += c2w[(c * 16 + i) * 5 + j] * y2[i * 15 + t + j];
        y3[o] = fmaxf(s, 0.f);
    }
    __syncthreads();

    // l1: coalesced stride-128 weight loads; i ascending -> bit-exact.
    for (int o = tid; o < 128; o += 256) {
        float s = l1b[o];
#pragma unroll 16
        for (int i = 0; i < 352; ++i) s += y3[i] * l1w[i * 128 + o];
        z[o] = fmaxf(s, 0.f);
    }
    __syncthreads();

    if (tid == 0) {
        float s = l2b[0];
#pragma unroll 4
        for (int i = 0; i < 128; ++i) s += z[i] * l2w[i];
        out[g] = 1.f / (1.f + expf(-s));
    }
}

extern "C" void kernel_launch(void* const* d_in, const int* in_sizes, int n_in,
                              void* d_out, int out_size, void* d_ws, size_t ws_size,
                              hipStream_t stream) {
    const float* x   = (const float*)d_in[0];
    const int* ei    = (const int*)d_in[1];
    const int* batch = (const int*)d_in[2];
    const float* W1  = (const float*)d_in[3];
    const float* b1  = (const float*)d_in[4];
    const float* W2  = (const float*)d_in[5];
    const float* b2  = (const float*)d_in[6];
    const float* W3  = (const float*)d_in[7];
    const float* b3  = (const float*)d_in[8];
    const float* W4  = (const float*)d_in[9];
    const float* b4  = (const float*)d_in[10];
    const float* c1w = (const float*)d_in[11];
    const float* c1b = (const float*)d_in[12];
    const float* c2w = (const float*)d_in[13];
    const float* c2b = (const float*)d_in[14];
    const float* l1w = (const float*)d_in[15];
    const float* l1b = (const float*)d_in[16];
    const float* l2w = (const float*)d_in[17];
    const float* l2b = (const float*)d_in[18];
    float* out = (float*)d_out;

    const int* srcp = ei;
    const int* dstp = ei + NE;

    // workspace layout
    char* w = (char*)d_ws;
    float* dinv      = (float*)w;               w += sizeof(float) * NN;
    float* htmpA     = (float*)w;               w += sizeof(float) * NN * 32;
    float* htmpB     = (float*)w;               w += sizeof(float) * NN * 32;
    float* h1        = (float*)w;               w += sizeof(float) * NN * 32;
    float* h2        = (float*)w;               w += sizeof(float) * NN * 32;  // ebuf aliases here
    float* h3        = (float*)w;               w += sizeof(float) * NN * 32;
    float* h4        = (float*)w;               w += sizeof(float) * NN;
    int*   rowptr    = (int*)w;                 w += sizeof(int) * (NN + 1);
    int*   hist1     = (int*)w;                 w += sizeof(int) * NBUCK * NB1;
    int*   offs      = (int*)w;                 w += sizeof(int) * NBUCK * NB1;
    int*   totals    = (int*)w;                 w += sizeof(int) * NBUCK;
    int*   bucketStart = (int*)w;               w += sizeof(int) * (NBUCK + 1);
    int*   csr_src   = (int*)w;                 w += sizeof(int) * NE;
    int*   starts    = (int*)w;                 w += sizeof(int) * (NG + 1);

    // ebuf (6.55 MB) aliases h2 (13.1 MB): h2 is first written by agg layer 2,
    // long after p2 has consumed ebuf.
    unsigned int* ebuf = (unsigned int*)h2;

    // CSR build (no global atomics) + dense1 + starts
    fused_front_kernel<<<NB1 + 800 + 400, 256, 0, stream>>>(dstp, hist1, x, W1, htmpA,
                                                            batch, starts);
    s1a_kernel<<<NBUCK, 256, 0, stream>>>(hist1, offs, totals);
    s1b_kernel<<<1, 256, 0, stream>>>(totals, bucketStart, rowptr);
    p1_kernel<<<NB1, 256, 0, stream>>>(srcp, dstp, offs, bucketStart, ebuf);
    p2_kernel<<<NBUCK, 256, 0, stream>>>(ebuf, bucketStart, csr_src, rowptr, dinv);

    // layer 1 agg (+ fused dense W2): htmpA -> h1, htmpB
    gcn_aggd_kernel<32><<<NN / 32, 256, 0, stream>>>(rowptr, csr_src, htmpA, dinv, b1,
                                                     W2, h1, htmpB);
    // layer 2 agg (+ fused dense W3): htmpB -> h2, htmpA
    gcn_aggd_kernel<32><<<NN / 32, 256, 0, stream>>>(rowptr, csr_src, htmpB, dinv, b2,
                                                     W3, h2, htmpA);
    // layer 3 agg (+ fused dense W4 32->1): htmpA -> h3, htmpB[0:NN]
    gcn_aggd_kernel<1><<<NN / 32, 256, 0, stream>>>(rowptr, csr_src, htmpA, dinv, b3,
                                                    W4, h3, htmpB);
    // layer 4 agg: htmpB[0:NN] -> h4
    gcn_agg1_kernel<<<NN / 256, 256, 0, stream>>>(rowptr, csr_src, htmpB, dinv, b4, h4);

    // fused sort-pool + CNN head
    pool_cnn_kernel<<<NG, 256, 0, stream>>>(h1, h2, h3, h4, starts,
                                            c1w, c1b, c2w, c2b,
                                            l1w, l1b, l2w, l2b, out);
}

// Round 16
// 221.316 us; speedup vs baseline: 1.0821x; 1.0191x over previous
//
#include <hip/hip_runtime.h>
#include <math.h>

#define NN 102400
#define NE 1638400
#define NG 2048
#define KTOP 30
#define NBUCK 400   // coarse buckets of 256 nodes (dst >> 8)
#define EPB 4096    // edges per pass-1 block
#define NB1 400     // NE / EPB

// ---------- fused front: coarse histogram + dense1 (LDS-staged x) + starts ----------
__global__ __launch_bounds__(256) void fused_front_kernel(
    const int* __restrict__ dst, int* __restrict__ hist1,
    const float* __restrict__ x, const float* __restrict__ W1,
    float* __restrict__ htmp,
    const int* __restrict__ batch, int* __restrict__ starts) {
    __shared__ float Wsh[128 * 32];   // 16384 B
    __shared__ float Xs[128 * 33];    // 16896 B (pad 33 breaks bank alias)
    __shared__ int hsh[NBUCK];        // 1600 B
    int bid = blockIdx.x;
    int tid = threadIdx.x;

    if (bid < NB1) {
        // ---- H1: coarse histogram ----
        for (int q = tid; q < NBUCK; q += 256) hsh[q] = 0;
        __syncthreads();
        const int4* dp = (const int4*)(dst + bid * EPB);
        for (int i4 = tid; i4 < EPB / 4; i4 += 256) {
            int4 dd = dp[i4];
            atomicAdd(&hsh[dd.x >> 8], 1);
            atomicAdd(&hsh[dd.y >> 8], 1);
            atomicAdd(&hsh[dd.z >> 8], 1);
            atomicAdd(&hsh[dd.w >> 8], 1);
        }
        __syncthreads();
        for (int q = tid; q < NBUCK; q += 256) hist1[q * NB1 + bid] = hsh[q];
    } else if (bid < NB1 + 800) {
        // ---- dense1: 128 -> 32; x staged via LDS (coalesced; r12/r13 lesson) ----
        int bidx = bid - NB1;
        int n_base = bidx * 128;
        for (int i = tid; i < 128 * 32; i += 256) Wsh[i] = W1[i];
        int jb = (tid >> 6) << 3;   // wave-uniform
        int q = tid & 63;
        float acc0[8], acc1[8];
#pragma unroll
        for (int j = 0; j < 8; ++j) { acc0[j] = 0.f; acc1[j] = 0.f; }
        for (int k0 = 0; k0 < 128; k0 += 32) {
            __syncthreads();
#pragma unroll
            for (int it = 0; it < 4; ++it) {
                int u = tid + 256 * it;       // 0..1023
                int row = u >> 3;             // 0..127
                int c4 = u & 7;               // 0..7
                float4 v = *(const float4*)&x[(size_t)(n_base + row) * 128 + k0 + c4 * 4];
                *(float4*)&Xs[row * 33 + c4 * 4] = v;
            }
            __syncthreads();
#pragma unroll 8
            for (int kk = 0; kk < 32; ++kk) {
                float v0 = Xs[q * 33 + kk];
                float v1 = Xs[(q + 64) * 33 + kk];
                float4 wlo = *(const float4*)&Wsh[(k0 + kk) * 32 + jb];
                float4 whi = *(const float4*)&Wsh[(k0 + kk) * 32 + jb + 4];
                acc0[0] += v0 * wlo.x; acc0[1] += v0 * wlo.y;
                acc0[2] += v0 * wlo.z; acc0[3] += v0 * wlo.w;
                acc0[4] += v0 * whi.x; acc0[5] += v0 * whi.y;
                acc0[6] += v0 * whi.z; acc0[7] += v0 * whi.w;
                acc1[0] += v1 * wlo.x; acc1[1] += v1 * wlo.y;
                acc1[2] += v1 * wlo.z; acc1[3] += v1 * wlo.w;
                acc1[4] += v1 * whi.x; acc1[5] += v1 * whi.y;
                acc1[6] += v1 * whi.z; acc1[7] += v1 * whi.w;
            }
        }
        int n0 = n_base + q;
        int n1 = n0 + 64;
        float4 o0 = {acc0[0], acc0[1], acc0[2], acc0[3]};
        float4 o1 = {acc0[4], acc0[5], acc0[6], acc0[7]};
        float4 o2 = {acc1[0], acc1[1], acc1[2], acc1[3]};
        float4 o3 = {acc1[4], acc1[5], acc1[6], acc1[7]};
        *(float4*)&htmp[(size_t)n0 * 32 + jb] = o0;
        *(float4*)&htmp[(size_t)n0 * 32 + jb + 4] = o1;
        *(float4*)&htmp[(size_t)n1 * 32 + jb] = o2;
        *(float4*)&htmp[(size_t)n1 * 32 + jb + 4] = o3;
    } else {
        // ---- starts ----
        int i = (bid - NB1 - 800) * 256 + tid;
        if (i < NN) {
            int c = batch[i];
            int p = (i == 0) ? -1 : batch[i - 1];
            for (int g = p + 1; g <= c; ++g) starts[g] = i;
            if (i == NN - 1) {
                for (int g = c + 1; g <= NG; ++g) starts[g] = NN;
            }
        }
    }
}

// ---------- S1a ----------
__global__ __launch_bounds__(256) void s1a_kernel(const int* __restrict__ hist1,
                                                  int* __restrict__ offs,
                                                  int* __restrict__ totals) {
    __shared__ int A[512], B[512];
    int q = blockIdx.x, tid = threadIdx.x;
    int i0 = tid, i1 = tid + 256;
    int v0 = (i0 < NB1) ? hist1[q * NB1 + i0] : 0;
    int v1 = (i1 < NB1) ? hist1[q * NB1 + i1] : 0;
    A[i0] = v0; A[i1] = v1;
    __syncthreads();
    int* cur = A; int* nxt = B;
    for (int off = 1; off < 512; off <<= 1) {
        nxt[i0] = cur[i0] + ((i0 >= off) ? cur[i0 - off] : 0);
        nxt[i1] = cur[i1] + cur[i1 - off];
        __syncthreads();
        int* t = cur; cur = nxt; nxt = t;
    }
    if (i0 < NB1) offs[q * NB1 + i0] = cur[i0] - v0;
    if (i1 < NB1) offs[q * NB1 + i1] = cur[i1] - v1;
    if (tid == 0) totals[q] = cur[511];
}

// ---------- S1b ----------
__global__ __launch_bounds__(256) void s1b_kernel(const int* __restrict__ totals,
                                                  int* __restrict__ bucketStart,
                                                  int* __restrict__ rowptr) {
    __shared__ int A[512], B[512];
    int tid = threadIdx.x;
    int i0 = tid, i1 = tid + 256;
    int v0 = (i0 < NBUCK) ? totals[i0] : 0;
    int v1 = (i1 < NBUCK) ? totals[i1] : 0;
    A[i0] = v0; A[i1] = v1;
    __syncthreads();
    int* cur = A; int* nxt = B;
    for (int off = 1; off < 512; off <<= 1) {
        nxt[i0] = cur[i0] + ((i0 >= off) ? cur[i0 - off] : 0);
        nxt[i1] = cur[i1] + cur[i1 - off];
        __syncthreads();
        int* t = cur; cur = nxt; nxt = t;
    }
    if (i0 < NBUCK) bucketStart[i0] = cur[i0] - v0;
    if (i1 < NBUCK) bucketStart[i1] = cur[i1] - v1;
    if (tid == 0) { bucketStart[NBUCK] = cur[511]; rowptr[NN] = cur[511]; }
}

// ---------- P1 ----------
__global__ __launch_bounds__(256) void p1_kernel(const int* __restrict__ src,
                                                 const int* __restrict__ dst,
                                                 const int* __restrict__ offs,
                                                 const int* __restrict__ bucketStart,
                                                 unsigned int* __restrict__ ebuf) {
    __shared__ int myoff[NBUCK];
    int b = blockIdx.x, tid = threadIdx.x;
    for (int q = tid; q < NBUCK; q += 256)
        myoff[q] = bucketStart[q] + offs[q * NB1 + b];
    __syncthreads();
    const int4* dp = (const int4*)(dst + b * EPB);
    const int4* sp = (const int4*)(src + b * EPB);
    for (int i4 = tid; i4 < EPB / 4; i4 += 256) {
        int4 dd = dp[i4];
        int4 ss = sp[i4];
        int p0 = atomicAdd(&myoff[dd.x >> 8], 1);
        int p1 = atomicAdd(&myoff[dd.y >> 8], 1);
        int p2 = atomicAdd(&myoff[dd.z >> 8], 1);
        int p3 = atomicAdd(&myoff[dd.w >> 8], 1);
        ebuf[p0] = ((unsigned int)(dd.x & 255) << 24) | (unsigned int)ss.x;
        ebuf[p1] = ((unsigned int)(dd.y & 255) << 24) | (unsigned int)ss.y;
        ebuf[p2] = ((unsigned int)(dd.z & 255) << 24) | (unsigned int)ss.z;
        ebuf[p3] = ((unsigned int)(dd.w & 255) << 24) | (unsigned int)ss.w;
    }
}

// ---------- P2 ----------
__global__ __launch_bounds__(256) void p2_kernel(const unsigned int* __restrict__ ebuf,
                                                 const int* __restrict__ bucketStart,
                                                 int* __restrict__ csr_src,
                                                 int* __restrict__ rowptr,
                                                 float* __restrict__ dinv) {
    __shared__ int fcnt[256];
    __shared__ int tmp[256];
    __shared__ int foff[256];
    int q = blockIdx.x, tid = threadIdx.x;
    int base = bucketStart[q];
    int ecnt = bucketStart[q + 1] - base;
    fcnt[tid] = 0;
    __syncthreads();
    for (int i = tid; i < ecnt; i += 256) {
        unsigned int e = ebuf[base + i];
        atomicAdd(&fcnt[e >> 24], 1);
    }
    __syncthreads();
    int c = fcnt[tid];
    int n = q * 256 + tid;
    dinv[n] = rsqrtf((float)c + 1.0f);
    tmp[tid] = c;
    __syncthreads();
    for (int off = 1; off < 256; off <<= 1) {
        int u = (tid >= off) ? tmp[tid - off] : 0;
        __syncthreads();
        tmp[tid] += u;
        __syncthreads();
    }
    int excl = base + tmp[tid] - c;
    rowptr[n] = excl;
    foff[tid] = excl;
    __syncthreads();
    for (int i = tid; i < ecnt; i += 256) {
        unsigned int e = ebuf[base + i];
        int pos = atomicAdd(&foff[e >> 24], 1);
        csr_src[pos] = (int)(e & 0xFFFFFF);
    }
}

// ---------- fused gather-aggregate + tanh + NEXT-layer dense epilogue ----------
template <int NEXT>  // 32 (-> full 32x32 dense) or 1 (-> 32->1 dense)
__global__ __launch_bounds__(256) void gcn_aggd_kernel(
    const int* __restrict__ rowptr, const int* __restrict__ csr_src,
    const float* __restrict__ htmp, const float* __restrict__ dinv,
    const float* __restrict__ b, const float* __restrict__ Wn,
    float* __restrict__ hout, float* __restrict__ htn) {
    __shared__ float Ws[32 * 32];
    __shared__ float Hs[32][36];
    int tid = threadIdx.x;
    if (NEXT == 32) {
        for (int i = tid; i < 1024; i += 256) Ws[i] = Wn[i];
    } else {
        if (tid < 32) Ws[tid] = Wn[tid];
    }
    int idx = blockIdx.x * 256 + tid;
    int n = idx >> 3, fg = (idx & 7) << 2;
    int beg = rowptr[n], end = rowptr[n + 1];
    float di = dinv[n];
    float4 acc = {0.f, 0.f, 0.f, 0.f};
    int i = beg;
    for (; i + 7 < end; i += 8) {
        int s[8];
#pragma unroll
        for (int k = 0; k < 8; ++k) s[k] = csr_src[i + k];
        float c[8];
#pragma unroll
        for (int k = 0; k < 8; ++k) c[k] = dinv[s[k]] * di;
        float4 v[8];
#pragma unroll
        for (int k = 0; k < 8; ++k) v[k] = *(const float4*)&htmp[(size_t)s[k] * 32 + fg];
#pragma unroll
        for (int k = 0; k < 8; ++k) {
            acc.x += v[k].x * c[k]; acc.y += v[k].y * c[k];
            acc.z += v[k].z * c[k]; acc.w += v[k].w * c[k];
        }
    }
    for (; i + 3 < end; i += 4) {
        int s0 = csr_src[i], s1 = csr_src[i + 1];
        int s2 = csr_src[i + 2], s3 = csr_src[i + 3];
        float c0 = dinv[s0] * di, c1 = dinv[s1] * di;
        float c2 = dinv[s2] * di, c3 = dinv[s3] * di;
        float4 v0 = *(const float4*)&htmp[(size_t)s0 * 32 + fg];
        float4 v1 = *(const float4*)&htmp[(size_t)s1 * 32 + fg];
        float4 v2 = *(const float4*)&htmp[(size_t)s2 * 32 + fg];
        float4 v3 = *(const float4*)&htmp[(size_t)s3 * 32 + fg];
        acc.x += v0.x * c0; acc.y += v0.y * c0; acc.z += v0.z * c0; acc.w += v0.w * c0;
        acc.x += v1.x * c1; acc.y += v1.y * c1; acc.z += v1.z * c1; acc.w += v1.w * c1;
        acc.x += v2.x * c2; acc.y += v2.y * c2; acc.z += v2.z * c2; acc.w += v2.w * c2;
        acc.x += v3.x * c3; acc.y += v3.y * c3; acc.z += v3.z * c3; acc.w += v3.w * c3;
    }
    for (; i < end; ++i) {
        int s = csr_src[i];
        float c = dinv[s] * di;
        float4 v = *(const float4*)&htmp[(size_t)s * 32 + fg];
        acc.x += v.x * c; acc.y += v.y * c; acc.z += v.z * c; acc.w += v.w * c;
    }
    float dd = di * di;
    float4 hs = *(const float4*)&htmp[(size_t)n * 32 + fg];
    float4 bb = *(const float4*)&b[fg];
    float4 o;
    o.x = tanhf(acc.x + hs.x * dd + bb.x);
    o.y = tanhf(acc.y + hs.y * dd + bb.y);
    o.z = tanhf(acc.z + hs.z * dd + bb.z);
    o.w = tanhf(acc.w + hs.w * dd + bb.w);
    *(float4*)&hout[(size_t)n * 32 + fg] = o;
    int nl = tid >> 3;
    *(float4*)&Hs[nl][fg] = o;
    __syncthreads();
    if (NEXT == 32) {
        int n2 = tid >> 3, j4 = (tid & 7) << 2;
        int gnode = blockIdx.x * 32 + n2;
        float4 r = {0.f, 0.f, 0.f, 0.f};
#pragma unroll
        for (int k = 0; k < 32; ++k) {
            float h = Hs[n2][k];
            float4 wv = *(const float4*)&Ws[k * 32 + j4];
            r.x += h * wv.x; r.y += h * wv.y; r.z += h * wv.z; r.w += h * wv.w;
        }
        *(float4*)&htn[(size_t)gnode * 32 + j4] = r;
    } else {
        if (tid < 32) {
            int gnode = blockIdx.x * 32 + tid;
            float s = 0.f;
#pragma unroll
            for (int k = 0; k < 32; ++k) s += Hs[tid][k] * Ws[k];
            htn[gnode] = s;
        }
    }
}

__global__ __launch_bounds__(256) void gcn_agg1_kernel(
    const int* __restrict__ rowptr, const int* __restrict__ csr_src,
    const float* __restrict__ htmp, const float* __restrict__ dinv,
    const float* __restrict__ b, float* __restrict__ hout) {
    int n = blockIdx.x * blockDim.x + threadIdx.x;
    if (n >= NN) return;
    int beg = rowptr[n], end = rowptr[n + 1];
    float di = dinv[n];
    float acc = 0.f;
    int i = beg;
    for (; i + 7 < end; i += 8) {
        int s[8];
#pragma unroll
        for (int k = 0; k < 8; ++k) s[k] = csr_src[i + k];
        float c[8], v[8];
#pragma unroll
        for (int k = 0; k < 8; ++k) c[k] = dinv[s[k]] * di;
#pragma unroll
        for (int k = 0; k < 8; ++k) v[k] = htmp[s[k]];
#pragma unroll
        for (int k = 0; k < 8; ++k) acc += v[k] * c[k];
    }
    for (; i < end; ++i) {
        int s = csr_src[i];
        acc += htmp[s] * (dinv[s] * di);
    }
    hout[n] = tanhf(acc + htmp[n] * di * di + b[0]);
}

// ---------- sort-pool + CNN head ----------
// LDS 20320 B -> block 20480 (8 blocks/CU). Key additions this round:
//  * conv1: 4 outputs per thread (120 threads) -> each P row / CW row read
//    feeds 2 outputs; LDS b128 instrs ~halved. Per-output f-order unchanged.
//  * conv2: c2w staged into the dead P-feature region (P[240..2800)) once
//    per block (coalesced) instead of 28K scattered global lane-loads;
//    y3/z relocate to the dead KY (y1) region.

#define PSTR 100

__global__ __launch_bounds__(256) void pool_cnn_kernel(
    const float* __restrict__ h1, const float* __restrict__ h2,
    const float* __restrict__ h3, const float* __restrict__ h4,
    const int* __restrict__ starts,
    const float* __restrict__ c1w, const float* __restrict__ c1b,
    const float* __restrict__ c2w, const float* __restrict__ c2b,
    const float* __restrict__ l1w, const float* __restrict__ l1b,
    const float* __restrict__ l2w, const float* __restrict__ l2b,
    float* __restrict__ out) {
    __shared__ float P[KTOP][PSTR];   // rows: [0..95]=feat, [96]=key, [97]=node
    __shared__ float CW[16 * PSTR];
    __shared__ float KY[480];
    float* keys = KY;
    float* y2  = &P[0][0];            // 240 floats (after conv1)
    float* c2s = &P[0][0] + 240;      // 2560 floats staged c2w (after conv1)
    float* y3  = KY;                  // 352 floats (after y2-stage; y1 dead)
    float* z   = KY + 352;            // 128 floats
    int g = blockIdx.x;
    int tid = threadIdx.x;

    int start = starts[g];
    int end = starts[g + 1];
    int cnt = end - start;

    for (int i = tid; i < KTOP * PSTR; i += 256) (&P[0][0])[i] = 0.f;
    for (int i = tid; i < 16 * 97; i += 256) {
        int c = i / 97, f = i % 97;
        CW[c * PSTR + f] = c1w[i];
    }
    bool fits = (cnt <= 480);
    if (fits) {
        for (int i = tid; i < cnt; i += 256) keys[i] = h4[start + i];
    }
    __syncthreads();

    // rank; stash (key,node) in P's pad columns (ranks distinct -> no conflicts)
    for (int i = tid; i < cnt; i += 256) {
        float key = fits ? keys[i] : h4[start + i];
        int rank = 0;
        if (fits) {
            for (int j = 0; j < cnt; ++j) {
                float kj = keys[j];
                rank += (kj > key) || (kj == key && j < i);
            }
        } else {
            for (int j = 0; j < cnt; ++j) {
                float kj = h4[start + j];
                rank += (kj > key) || (kj == key && j < i);
            }
        }
        if (rank < KTOP) {
            P[rank][96] = key;
            P[rank][97] = __int_as_float(start + i);
        }
    }
    __syncthreads();

    // cooperative P-fill: nsel rows x 24 float4 over all 256 threads
    int nsel = (cnt < KTOP) ? cnt : KTOP;
    for (int u = tid; u < nsel * 24; u += 256) {
        int r = u / 24, q = u % 24;
        int node = __float_as_int(P[r][97]);
        const float* srcp = (q < 8) ? h1 : (q < 16) ? h2 : h3;
        int qq = q & 7;
        float4 v = *(const float4*)(srcp + (size_t)node * 32 + 4 * qq);
        *(float4*)&P[r][(q < 8 ? 0 : (q < 16 ? 32 : 64)) + 4 * qq] = v;
    }
    __syncthreads();

    // conv1: 4 outputs/thread (t0,t0+15)x(c0,c0+8) -> each LDS row read feeds
    // two outputs. Banks: 8 distinct t0 rows at 400B stride (banks 4*t0) and
    // 8 distinct c0 rows -> conflict-free. Per-output f ascending -> bit-exact.
    if (tid < 120) {
        int t0 = tid >> 3;       // 0..14
        int c0 = tid & 7;        // 0..7
        const float* PrA = &P[t0][0];
        const float* PrB = &P[t0 + 15][0];
        const float* WrA = &CW[c0 * PSTR];
        const float* WrB = &CW[(c0 + 8) * PSTR];
        float bA = c1b[c0], bB = c1b[c0 + 8];
        float sAA = bA, sAB = bB, sBA = bA, sBB = bB;
#pragma unroll
        for (int f4 = 0; f4 < 24; ++f4) {
            float4 pA = *(const float4*)(PrA + 4 * f4);
            float4 pB = *(const float4*)(PrB + 4 * f4);
            float4 wA = *(const float4*)(WrA + 4 * f4);
            float4 wB = *(const float4*)(WrB + 4 * f4);
            sAA += wA.x * pA.x; sAA += wA.y * pA.y; sAA += wA.z * pA.z; sAA += wA.w * pA.w;
            sAB += wB.x * pA.x; sAB += wB.y * pA.y; sAB += wB.z * pA.z; sAB += wB.w * pA.w;
            sBA += wA.x * pB.x; sBA += wA.y * pB.y; sBA += wA.z * pB.z; sBA += wA.w * pB.w;
            sBB += wB.x * pB.x; sBB += wB.y * pB.y; sBB += wB.z * pB.z; sBB += wB.w * pB.w;
        }
        float kA = PrA[96], kB = PrB[96];
        sAA += WrA[96] * kA; sAB += WrB[96] * kA;
        sBA += WrA[96] * kB; sBB += WrB[96] * kB;
        KY[c0 * KTOP + t0]            = fmaxf(sAA, 0.f);
        KY[(c0 + 8) * KTOP + t0]      = fmaxf(sAB, 0.f);
        KY[c0 * KTOP + t0 + 15]       = fmaxf(sBA, 0.f);
        KY[(c0 + 8) * KTOP + t0 + 15] = fmaxf(sBB, 0.f);
    }
    __syncthreads();

    // y2 <- maxpool(y1) into P[0..240); stage c2w into P[240..2800) (dead rows)
    for (int o = tid; o < 16 * 15; o += 256) {
        int c = o / 15, t = o % 15;
        y2[o] = fmaxf(KY[c * KTOP + 2 * t], KY[c * KTOP + 2 * t + 1]);
    }
    for (int i = tid; i < 2560; i += 256) c2s[i] = c2w[i];
    __syncthreads();

    // conv2: weights from LDS; y3 into KY (y1 dead)
    for (int o = tid; o < 32 * 11; o += 256) {
        int c = o / 11, t = o % 11;
        float s = c2b[c];
#pragma unroll
        for (int i = 0; i < 16; ++i)
#pragma unroll
            for (int j = 0; j < 5; ++j)
                s += c2s[(c * 16 + i) * 5 + j] * y2[i * 15 + t + j];
        y3[o] = fmaxf(s, 0.f);
    }
    __syncthreads();

    // l1: coalesced stride-128 weight loads; i ascending -> bit-exact.
    for (int o = tid; o < 128; o += 256) {
        float s = l1b[o];
#pragma unroll 16
        for (int i = 0; i < 352; ++i) s += y3[i] * l1w[i * 128 + o];
        z[o] = fmaxf(s, 0.f);
    }
    __syncthreads();

    if (tid == 0) {
        float s = l2b[0];
#pragma unroll 4
        for (int i = 0; i < 128; ++i) s += z[i] * l2w[i];
        out[g] = 1.f / (1.f + expf(-s));
    }
}

extern "C" void kernel_launch(void* const* d_in, const int* in_sizes, int n_in,
                              void* d_out, int out_size, void* d_ws, size_t ws_size,
                              hipStream_t stream) {
    const float* x   = (const float*)d_in[0];
    const int* ei    = (const int*)d_in[1];
    const int* batch = (const int*)d_in[2];
    const float* W1  = (const float*)d_in[3];
    const float* b1  = (const float*)d_in[4];
    const float* W2  = (const float*)d_in[5];
    const float* b2  = (const float*)d_in[6];
    const float* W3  = (const float*)d_in[7];
    const float* b3  = (const float*)d_in[8];
    const float* W4  = (const float*)d_in[9];
    const float* b4  = (const float*)d_in[10];
    const float* c1w = (const float*)d_in[11];
    const float* c1b = (const float*)d_in[12];
    const float* c2w = (const float*)d_in[13];
    const float* c2b = (const float*)d_in[14];
    const float* l1w = (const float*)d_in[15];
    const float* l1b = (const float*)d_in[16];
    const float* l2w = (const float*)d_in[17];
    const float* l2b = (const float*)d_in[18];
    float* out = (float*)d_out;

    const int* srcp = ei;
    const int* dstp = ei + NE;

    // workspace layout
    char* w = (char*)d_ws;
    float* dinv      = (float*)w;               w += sizeof(float) * NN;
    float* htmpA     = (float*)w;               w += sizeof(float) * NN * 32;
    float* htmpB     = (float*)w;               w += sizeof(float) * NN * 32;
    float* h1        = (float*)w;               w += sizeof(float) * NN * 32;
    float* h2        = (float*)w;               w += sizeof(float) * NN * 32;  // ebuf aliases here
    float* h3        = (float*)w;               w += sizeof(float) * NN * 32;
    float* h4        = (float*)w;               w += sizeof(float) * NN;
    int*   rowptr    = (int*)w;                 w += sizeof(int) * (NN + 1);
    int*   hist1     = (int*)w;                 w += sizeof(int) * NBUCK * NB1;
    int*   offs      = (int*)w;                 w += sizeof(int) * NBUCK * NB1;
    int*   totals    = (int*)w;                 w += sizeof(int) * NBUCK;
    int*   bucketStart = (int*)w;               w += sizeof(int) * (NBUCK + 1);
    int*   csr_src   = (int*)w;                 w += sizeof(int) * NE;
    int*   starts    = (int*)w;                 w += sizeof(int) * (NG + 1);

    // ebuf (6.55 MB) aliases h2 (13.1 MB): h2 is first written by agg layer 2,
    // long after p2 has consumed ebuf.
    unsigned int* ebuf = (unsigned int*)h2;

    // CSR build (no global atomics) + dense1 + starts
    fused_front_kernel<<<NB1 + 800 + 400, 256, 0, stream>>>(dstp, hist1, x, W1, htmpA,
                                                            batch, starts);
    s1a_kernel<<<NBUCK, 256, 0, stream>>>(hist1, offs, totals);
    s1b_kernel<<<1, 256, 0, stream>>>(totals, bucketStart, rowptr);
    p1_kernel<<<NB1, 256, 0, stream>>>(srcp, dstp, offs, bucketStart, ebuf);
    p2_kernel<<<NBUCK, 256, 0, stream>>>(ebuf, bucketStart, csr_src, rowptr, dinv);

    // layer 1 agg (+ fused dense W2): htmpA -> h1, htmpB
    gcn_aggd_kernel<32><<<NN / 32, 256, 0, stream>>>(rowptr, csr_src, htmpA, dinv, b1,
                                                     W2, h1, htmpB);
    // layer 2 agg (+ fused dense W3): htmpB -> h2, htmpA
    gcn_aggd_kernel<32><<<NN / 32, 256, 0, stream>>>(rowptr, csr_src, htmpB, dinv, b2,
                                                     W3, h2, htmpA);
    // layer 3 agg (+ fused dense W4 32->1): htmpA -> h3, htmpB[0:NN]
    gcn_aggd_kernel<1><<<NN / 32, 256, 0, stream>>>(rowptr, csr_src, htmpA, dinv, b3,
                                                    W4, h3, htmpB);
    // layer 4 agg: htmpB[0:NN] -> h4
    gcn_agg1_kernel<<<NN / 256, 256, 0, stream>>>(rowptr, csr_src, htmpB, dinv, b4, h4);

    // fused sort-pool + CNN head
    pool_cnn_kernel<<<NG, 256, 0, stream>>>(h1, h2, h3, h4, starts,
                                            c1w, c1b, c2w, c2b,
                                            l1w, l1b, l2w, l2b, out);
}